// Round 6
// baseline (323.384 us; speedup 1.0000x reference)
//
#include <hip/hip_runtime.h>
#include <hip/hip_fp16.h>

// B=4, L=2048, D=1024.  All GEMMs: 2-phase 128x128 fp16-MFMA, 4 waves,
// 2.4 blocks/CU co-residency (the proven round-2 structure), plane LDS
// layout [kg][row][8] (HW-verified 0 bank conflicts, gload_lds-compatible).
//  cvt (1 dispatch): X, Wkqv, Wproj -> fp16
//  G1: kqvh = f16(Xh @ Wkqvh^T + bkqv)              8192x3072
//  G2: Sh[b] = f16(Qh@Kh^T * 1/32), mask col>=vlen -> -30000 (f16-safe),
//      fully-masked 128-col tiles skipped
//  SM: masked row softmax (f16 in) -> attn f16
//  G4: out2h = f16(perm(attn @ V)), K limited to ceil(vlen/32) tiles,
//      V reg-staged + pack-transposed (linear [n][32] layout)
//  G5: out = out2h @ Wprojh^T + bproj (f32 -> d_out)

typedef _Float16 f16;
typedef _Float16 f16x8 __attribute__((ext_vector_type(8)));
typedef float f32x4 __attribute__((ext_vector_type(4)));

__device__ __forceinline__ void gload16(const f16* g, f16* l) {
  __builtin_amdgcn_global_load_lds(
      (const __attribute__((address_space(1))) unsigned int*)g,
      (__attribute__((address_space(3))) unsigned int*)l, 16, 0, 0);
}

#define BM 128
#define BN 128
#define BK 32

// BT: B operand is V (K-major): reg-stage + pack-transpose into linear
//     [n][32] LDS. Otherwise B is (N,K) row-major: plane-layout gload_lds.
// A is always plane-layout gload_lds.
template <bool BT, bool BIAS, bool MASK, bool PERM, bool OUTF16, bool KLIM>
__global__ __launch_bounds__(256) void mfma_gemm(
    const f16* __restrict__ A, long lda, const f16* __restrict__ B, long ldb,
    void* __restrict__ Cv, long ldc, const float* __restrict__ bias,
    const int* __restrict__ valid_lens, float scale, int K, long strideA,
    long strideB, long strideC) {
  __shared__ __align__(16) f16 As[2][BM * BK];
  __shared__ __align__(16) f16 Bs[2][BN * BK];

  const int tid = threadIdx.x;
  const int w = tid >> 6;    // wave 0..3 (= kg plane for staging)
  const int ln = tid & 63;
  const int m0 = blockIdx.y * BM;
  const int n0 = blockIdx.x * BN;
  const int bz = blockIdx.z;

  const int vlen = (MASK || KLIM) ? valid_lens[bz] : 0;
  if (MASK && n0 >= vlen) return;  // fully-masked tile: softmax never reads it

  A += (long)bz * strideA;
  B += (long)bz * strideB;

  int nk = K >> 5;
  if (KLIM) {
    int t = (vlen + BK - 1) >> 5;
    nk = t < nk ? t : nk;
  }

  // V pack-transpose staging indices
  const int kp = tid & 15;  // k-pair index (k = 2*kp, 2*kp+1)
  const int dg = tid >> 4;  // d-group (8 cols)

  f32x4 acc[4][4];
#pragma unroll
  for (int i = 0; i < 4; ++i)
#pragma unroll
    for (int j = 0; j < 4; ++j) acc[i][j] = (f32x4){0.f, 0.f, 0.f, 0.f};

  uint4 va, vb2;

  // plane layout: element (row r, col kg*8+e) at [kg*1024 + r*8 + e]
  auto stageA = [&](int buf, int kk) {
#pragma unroll
    for (int c = 0; c < 2; ++c)
      gload16(A + (long)(m0 + c * 64 + ln) * lda + kk + w * 8,
              &As[buf][w * 1024 + c * 512]);
  };
  auto stageB = [&](int buf, int kk) {
#pragma unroll
    for (int c = 0; c < 2; ++c)
      gload16(B + (long)(n0 + c * 64 + ln) * ldb + kk + w * 8,
              &Bs[buf][w * 1024 + c * 512]);
  };
  auto loadV = [&](int kk) {
    const f16* p = B + (long)(kk + 2 * kp) * ldb + n0 + dg * 8;
    va = *(const uint4*)p;
    vb2 = *(const uint4*)(p + ldb);
  };
  auto writeV = [&](int buf) {  // linear [n][32] layout
    unsigned int* bw = (unsigned int*)&Bs[buf][0];
    const unsigned int ax[4] = {va.x, va.y, va.z, va.w};
    const unsigned int bx[4] = {vb2.x, vb2.y, vb2.z, vb2.w};
#pragma unroll
    for (int j = 0; j < 4; ++j) {
      unsigned int lo = (ax[j] & 0xffffu) | (bx[j] << 16);
      unsigned int hi = (ax[j] >> 16) | (bx[j] & 0xffff0000u);
      bw[(dg * 8 + 2 * j) * 16 + kp] = lo;
      bw[(dg * 8 + 2 * j + 1) * 16 + kp] = hi;
    }
  };

  stageA(0, 0);
  if (!BT) {
    stageB(0, 0);
  } else {
    loadV(0);
    writeV(0);
  }
  __syncthreads();

  const int wm = (w >> 1) * 64;
  const int wn = (w & 1) * 64;
  const int lr = ln & 15;   // fragment row/col within 16
  const int kg = ln >> 4;   // k-group 0..3

  for (int kt = 0; kt < nk; ++kt) {
    const int cur = kt & 1;
    const int nxt = cur ^ 1;
    const bool more = (kt + 1) < nk;
    if (more) {
      stageA(nxt, (kt + 1) << 5);
      if (!BT)
        stageB(nxt, (kt + 1) << 5);
      else
        loadV((kt + 1) << 5);
    }
    f16x8 af[4], bff[4];
#pragma unroll
    for (int i = 0; i < 4; ++i)
      af[i] = *(const f16x8*)&As[cur][kg * 1024 + (wm + i * 16 + lr) * 8];
#pragma unroll
    for (int j = 0; j < 4; ++j) {
      if constexpr (BT)
        bff[j] = *(const f16x8*)&Bs[cur][(wn + j * 16 + lr) * 32 + kg * 8];
      else
        bff[j] = *(const f16x8*)&Bs[cur][kg * 1024 + (wn + j * 16 + lr) * 8];
    }
#pragma unroll
    for (int i = 0; i < 4; ++i)
#pragma unroll
      for (int j = 0; j < 4; ++j)
        acc[i][j] = __builtin_amdgcn_mfma_f32_16x16x32_f16(af[i], bff[j],
                                                           acc[i][j], 0, 0, 0);
    if (BT && more) writeV(nxt);
    __syncthreads();
  }

  // epilogue (C/D: col = ln&15, row = (ln>>4)*4 + r)
#pragma unroll
  for (int i = 0; i < 4; ++i) {
#pragma unroll
    for (int j = 0; j < 4; ++j) {
      const int col = n0 + wn + j * 16 + lr;
      const float bv = BIAS ? bias[col] : 0.0f;
#pragma unroll
      for (int r = 0; r < 4; ++r) {
        const int row = m0 + wm + i * 16 + kg * 4 + r;
        float c = acc[i][j][r];
        if (MASK) c = (col >= vlen) ? -30000.0f : c * scale;  // f16-safe fill
        if (BIAS) c += bv;
        if (PERM) {
          const long idx =
              ((long)bz * 2048 + 2 * col + (row >> 10)) * 1024 + (row & 1023);
          ((f16*)Cv)[idx] = (f16)c;
        } else {
          const long idx = (long)bz * strideC + (long)row * ldc + col;
          if (OUTF16)
            ((f16*)Cv)[idx] = (f16)c;
          else
            ((float*)Cv)[idx] = c;
        }
      }
    }
  }
}

// ================== softmax (f16 scores in, f16 attn out) ==================
__global__ __launch_bounds__(256) void softmax_rows(
    const f16* __restrict__ S, f16* __restrict__ attn,
    const int* __restrict__ vlens) {
  const long row = blockIdx.x;
  const int b = (int)(row >> 11);
  const int vlen = vlens[b];
  const f16* p = S + row * 2048;
  const int tid = threadIdx.x;
  const int wave = tid >> 6, lane = tid & 63;
  const int c0 = tid * 8;

  float v[8];
  if (c0 + 8 <= vlen) {
    const f16x8 a = *(const f16x8*)(p + c0);
#pragma unroll
    for (int j = 0; j < 8; ++j) v[j] = (float)a[j];
  } else {
#pragma unroll
    for (int j = 0; j < 8; ++j)
      v[j] = (c0 + j < vlen) ? (float)p[c0 + j] : -1000000.0f;
  }

  float mx = v[0];
#pragma unroll
  for (int j = 1; j < 8; ++j) mx = fmaxf(mx, v[j]);
#pragma unroll
  for (int o = 1; o < 64; o <<= 1) mx = fmaxf(mx, __shfl_xor(mx, o));
  __shared__ float redm[4];
  if (lane == 0) redm[wave] = mx;
  __syncthreads();
  mx = fmaxf(fmaxf(redm[0], redm[1]), fmaxf(redm[2], redm[3]));

  float s = 0.f;
#pragma unroll
  for (int j = 0; j < 8; ++j) {
    v[j] = __expf(v[j] - mx);
    s += v[j];
  }
#pragma unroll
  for (int o = 1; o < 64; o <<= 1) s += __shfl_xor(s, o);
  __shared__ float reds[4];
  if (lane == 0) reds[wave] = s;
  __syncthreads();
  s = reds[0] + reds[1] + reds[2] + reds[3];

  const float inv = 1.0f / s;
  f16x8 ov;
#pragma unroll
  for (int j = 0; j < 8; ++j) ov[j] = (f16)(v[j] * inv);
  *(f16x8*)(attn + row * 2048 + c0) = ov;
}

// ================== fused f32->f16 convert (1 dispatch) ==================
__global__ __launch_bounds__(256) void cvt_all(
    const float* __restrict__ X, const float* __restrict__ W1,
    const float* __restrict__ W2, f16* __restrict__ Xh, f16* __restrict__ W1h,
    f16* __restrict__ W2h) {
  const int bid = blockIdx.x;
  const float* s;
  f16* d;
  int base;
  if (bid < 4096) {
    s = X; d = Xh; base = bid;
  } else if (bid < 5632) {
    s = W1; d = W1h; base = bid - 4096;
  } else {
    s = W2; d = W2h; base = bid - 5632;
  }
  const int i = (base * 256 + threadIdx.x) * 8;
  const float4 a = *(const float4*)(s + i);
  const float4 b = *(const float4*)(s + i + 4);
  f16x8 o;
  o[0] = (f16)a.x; o[1] = (f16)a.y; o[2] = (f16)a.z; o[3] = (f16)a.w;
  o[4] = (f16)b.x; o[5] = (f16)b.y; o[6] = (f16)b.z; o[7] = (f16)b.w;
  *(f16x8*)(d + i) = o;
}

extern "C" void kernel_launch(void* const* d_in, const int* in_sizes, int n_in,
                              void* d_out, int out_size, void* d_ws,
                              size_t ws_size, hipStream_t stream) {
  const float* X = (const float*)d_in[0];      // (4,2048,1024)
  const int* vlens = (const int*)d_in[1];      // (4,)
  const float* Wkqv = (const float*)d_in[2];   // (3072,1024)
  const float* bkqv = (const float*)d_in[3];   // (3072,)
  const float* Wproj = (const float*)d_in[4];  // (1024,1024)
  const float* bproj = (const float*)d_in[5];  // (1024,)
  float* out = (float*)d_out;                  // (4,2048,1024) f32

  char* w = (char*)d_ws;
  f16* Xh = (f16*)w;      w += 8192L * 1024 * 2;
  f16* Wkqvh = (f16*)w;   w += 3072L * 1024 * 2;
  f16* Wprojh = (f16*)w;  w += 1024L * 1024 * 2;
  f16* kqvh = (f16*)w;    w += 8192L * 3072 * 2;
  f16* attnh = (f16*)w;   w += 4L * 2048 * 2048 * 2;
  f16* out2h = (f16*)w;   w += 8192L * 1024 * 2;
  f16* Sh = (f16*)w;      // 4*2048*2048 f16

  cvt_all<<<6144, 256, 0, stream>>>(X, Wkqv, Wproj, Xh, Wkqvh, Wprojh);

  // G1: kqvh = f16(Xh @ Wkqvh^T + bkqv)   M=8192 N=3072 K=1024
  mfma_gemm<false, true, false, false, true, false>
      <<<dim3(24, 64, 1), 256, 0, stream>>>(Xh, 1024, Wkqvh, 1024, kqvh, 3072,
                                            bkqv, nullptr, 1.0f, 1024, 0, 0, 0);

  // G2: Sh[b] = f16(Qh @ Kh^T * 1/32), masked   M=N=2048 K=1024
  mfma_gemm<false, false, true, false, true, false>
      <<<dim3(16, 16, 4), 256, 0, stream>>>(
          kqvh + 1024, 3072, kqvh, 3072, Sh, 2048, nullptr, vlens, 0.03125f,
          1024, 2048L * 3072, 2048L * 3072, 2048L * 2048);

  // SM: masked softmax rows (f16 in) -> fp16 attn
  softmax_rows<<<8192, 256, 0, stream>>>(Sh, attnh, vlens);

  // G4: out2h = f16(perm(attn @ V))   M=2048 N=1024 K<=2048 (vlen-limited)
  mfma_gemm<true, false, false, true, true, true>
      <<<dim3(8, 16, 4), 256, 0, stream>>>(
          attnh, 2048, kqvh + 2048, 3072, out2h, 1024, nullptr, vlens, 1.0f,
          2048, 2048L * 2048, 2048L * 3072, 2048L * 1024);

  // G5: out = out2h @ Wprojh^T + bproj   M=8192 N=1024 K=1024 (f32 out)
  mfma_gemm<false, true, false, false, false, false>
      <<<dim3(8, 64, 1), 256, 0, stream>>>(out2h, 1024, Wprojh, 1024, out,
                                           1024, bproj, nullptr, 1.0f, 1024, 0,
                                           0, 0);
}

// Round 7
// 234.261 us; speedup vs baseline: 1.3804x; 1.3804x over previous
//
#include <hip/hip_runtime.h>
#include <hip/hip_fp16.h>

// B=4, L=2048, D=1024.  Round-2 proven 2-phase 128x128 fp16-MFMA GEMM
// structure (multi-block-per-CU overlap; [row][32] LDS layout — conflicted
// reads are NOT on the 2ph critical path, HW-verified rounds 2/6), plus
// orthogonal wins: f16 score matrix, f16-in softmax, single fused cvt.
//  cvt (1 dispatch): X, Wkqv, Wproj -> fp16
//  G1: kqvh = f16(Xh @ Wkqvh^T + bkqv)              8192x3072
//  G2: Sh[b] = f16(Qh@Kh^T * 1/32), mask col>=vlen -> -30000 (f16-safe),
//      fully-masked 128-col tiles skipped
//  SM: masked row softmax (f16 in) -> attn f16
//  G4: out2h = f16(perm(attn @ V)), K limited to ceil(vlen/32) tiles,
//      V reg-staged + pack-transposed ([n][32] layout)
//  G5: out = out2h @ Wprojh^T + bproj (f32 -> d_out)

typedef _Float16 f16;
typedef _Float16 f16x8 __attribute__((ext_vector_type(8)));
typedef float f32x4 __attribute__((ext_vector_type(4)));

#define BM 128
#define BN 128
#define BK 32

__device__ __forceinline__ void gload16(const f16* g, f16* l) {
  __builtin_amdgcn_global_load_lds(
      (const __attribute__((address_space(1))) unsigned int*)g,
      (__attribute__((address_space(3))) unsigned int*)l, 16, 0, 0);
}

// BT: B operand is V (K-major, reg-stage + pack-transpose). Otherwise B is
//     (N,K) row-major fp16, staged via global_load_lds (round-2 pattern:
//     4 lanes per row, 64B contiguous per row -> 16 segments/instr).
// MASK: c = (col>=vlen) ? -30000 : c*scale; skip tile if n0>=vlen.
// BIAS: c += bias[col]. PERM: swapaxes-reshape write. OUTF16: f16 C.
// KLIM: K-loop limited to ceil(vlen/BK) tiles.
template <bool BT, bool BIAS, bool MASK, bool PERM, bool OUTF16, bool KLIM>
__global__ __launch_bounds__(256) void mfma_gemm(
    const f16* __restrict__ A, long lda, const f16* __restrict__ B, long ldb,
    void* __restrict__ Cv, long ldc, const float* __restrict__ bias,
    const int* __restrict__ valid_lens, float scale, int K, long strideA,
    long strideB, long strideC) {
  __shared__ __align__(16) f16 As[2][BM * BK];
  __shared__ __align__(16) f16 Bs[2][BN * BK];

  const int tid = threadIdx.x;
  const int w = tid >> 6;
  const int ln = tid & 63;
  const int m0 = blockIdx.y * BM;
  const int n0 = blockIdx.x * BN;
  const int bz = blockIdx.z;

  const int vlen = (MASK || KLIM) ? valid_lens[bz] : 0;
  if (MASK && n0 >= vlen) return;  // fully-masked tile: softmax never reads it

  A += (long)bz * strideA;
  B += (long)bz * strideB;

  int nk = K >> 5;
  if (KLIM) {
    int t = (vlen + BK - 1) >> 5;
    nk = t < nk ? t : nk;
  }

  // V pack-transpose staging indices
  const int kp = tid & 15;  // k-pair index (k = 2*kp, 2*kp+1)
  const int dg = tid >> 4;  // d-group (8 cols)

  f32x4 acc[4][4];
#pragma unroll
  for (int i = 0; i < 4; ++i)
#pragma unroll
    for (int j = 0; j < 4; ++j) acc[i][j] = (f32x4){0.f, 0.f, 0.f, 0.f};

  uint4 va, vb2;

  auto stageA = [&](int buf, int kk) {
#pragma unroll
    for (int r = 0; r < 2; ++r)
      gload16(A + (long)(m0 + r * 64 + w * 16 + (ln >> 2)) * lda + kk +
                  (ln & 3) * 8,
              &As[buf][(r * 64 + w * 16) * BK]);
  };
  auto stageB = [&](int buf, int kk) {
#pragma unroll
    for (int r = 0; r < 2; ++r)
      gload16(B + (long)(n0 + r * 64 + w * 16 + (ln >> 2)) * ldb + kk +
                  (ln & 3) * 8,
              &Bs[buf][(r * 64 + w * 16) * BK]);
  };
  auto loadV = [&](int kk) {
    const f16* p = B + (long)(kk + 2 * kp) * ldb + n0 + dg * 8;
    va = *(const uint4*)p;
    vb2 = *(const uint4*)(p + ldb);
  };
  auto writeV = [&](int buf) {  // [n][32] layout
    unsigned int* bw = (unsigned int*)&Bs[buf][0];
    const unsigned int ax[4] = {va.x, va.y, va.z, va.w};
    const unsigned int bx[4] = {vb2.x, vb2.y, vb2.z, vb2.w};
#pragma unroll
    for (int j = 0; j < 4; ++j) {
      unsigned int lo = (ax[j] & 0xffffu) | (bx[j] << 16);
      unsigned int hi = (ax[j] >> 16) | (bx[j] & 0xffff0000u);
      bw[(dg * 8 + 2 * j) * 16 + kp] = lo;
      bw[(dg * 8 + 2 * j + 1) * 16 + kp] = hi;
    }
  };

  stageA(0, 0);
  if (!BT) {
    stageB(0, 0);
  } else {
    loadV(0);
    writeV(0);
  }
  __syncthreads();

  const int wm = (w >> 1) * 64;
  const int wn = (w & 1) * 64;

  for (int kt = 0; kt < nk; ++kt) {
    const int cur = kt & 1;
    const int nxt = cur ^ 1;
    const bool more = (kt + 1) < nk;
    if (more) {
      stageA(nxt, (kt + 1) << 5);
      if (!BT)
        stageB(nxt, (kt + 1) << 5);
      else
        loadV((kt + 1) << 5);
    }
    f16x8 af[4], bff[4];
#pragma unroll
    for (int i = 0; i < 4; ++i)
      af[i] = *(const f16x8*)&As[cur][(wm + i * 16 + (ln & 15)) * BK +
                                      (ln >> 4) * 8];
#pragma unroll
    for (int j = 0; j < 4; ++j)
      bff[j] = *(const f16x8*)&Bs[cur][(wn + j * 16 + (ln & 15)) * BK +
                                       (ln >> 4) * 8];
#pragma unroll
    for (int i = 0; i < 4; ++i)
#pragma unroll
      for (int j = 0; j < 4; ++j)
        acc[i][j] = __builtin_amdgcn_mfma_f32_16x16x32_f16(af[i], bff[j],
                                                           acc[i][j], 0, 0, 0);
    if (BT && more) writeV(nxt);
    __syncthreads();
  }

  // epilogue (C/D: col = ln&15, row = (ln>>4)*4 + r)
  const int lq = ln >> 4;
  const int lc = ln & 15;
#pragma unroll
  for (int i = 0; i < 4; ++i) {
#pragma unroll
    for (int j = 0; j < 4; ++j) {
      const int col = n0 + wn + j * 16 + lc;
      const float bv = BIAS ? bias[col] : 0.0f;
#pragma unroll
      for (int r = 0; r < 4; ++r) {
        const int row = m0 + wm + i * 16 + lq * 4 + r;
        float c = acc[i][j][r];
        if (MASK) c = (col >= vlen) ? -30000.0f : c * scale;  // f16-safe fill
        if (BIAS) c += bv;
        if (PERM) {
          const long idx =
              ((long)bz * 2048 + 2 * col + (row >> 10)) * 1024 + (row & 1023);
          ((f16*)Cv)[idx] = (f16)c;
        } else {
          const long idx = (long)bz * strideC + (long)row * ldc + col;
          if (OUTF16)
            ((f16*)Cv)[idx] = (f16)c;
          else
            ((float*)Cv)[idx] = c;
        }
      }
    }
  }
}

// ================== softmax (f16 scores in, f16 attn out) ==================
__global__ __launch_bounds__(256) void softmax_rows(
    const f16* __restrict__ S, f16* __restrict__ attn,
    const int* __restrict__ vlens) {
  const long row = blockIdx.x;
  const int b = (int)(row >> 11);
  const int vlen = vlens[b];
  const f16* p = S + row * 2048;
  const int tid = threadIdx.x;
  const int wave = tid >> 6, lane = tid & 63;
  const int c0 = tid * 8;

  float v[8];
  if (c0 + 8 <= vlen) {
    const f16x8 a = *(const f16x8*)(p + c0);
#pragma unroll
    for (int j = 0; j < 8; ++j) v[j] = (float)a[j];
  } else {
#pragma unroll
    for (int j = 0; j < 8; ++j)
      v[j] = (c0 + j < vlen) ? (float)p[c0 + j] : -1000000.0f;
  }

  float mx = v[0];
#pragma unroll
  for (int j = 1; j < 8; ++j) mx = fmaxf(mx, v[j]);
#pragma unroll
  for (int o = 1; o < 64; o <<= 1) mx = fmaxf(mx, __shfl_xor(mx, o));
  __shared__ float redm[4];
  if (lane == 0) redm[wave] = mx;
  __syncthreads();
  mx = fmaxf(fmaxf(redm[0], redm[1]), fmaxf(redm[2], redm[3]));

  float s = 0.f;
#pragma unroll
  for (int j = 0; j < 8; ++j) {
    v[j] = __expf(v[j] - mx);
    s += v[j];
  }
#pragma unroll
  for (int o = 1; o < 64; o <<= 1) s += __shfl_xor(s, o);
  __shared__ float reds[4];
  if (lane == 0) reds[wave] = s;
  __syncthreads();
  s = reds[0] + reds[1] + reds[2] + reds[3];

  const float inv = 1.0f / s;
  f16x8 ov;
#pragma unroll
  for (int j = 0; j < 8; ++j) ov[j] = (f16)(v[j] * inv);
  *(f16x8*)(attn + row * 2048 + c0) = ov;
}

// ================== fused f32->f16 convert (1 dispatch) ==================
__global__ __launch_bounds__(256) void cvt_all(
    const float* __restrict__ X, const float* __restrict__ W1,
    const float* __restrict__ W2, f16* __restrict__ Xh, f16* __restrict__ W1h,
    f16* __restrict__ W2h) {
  const int bid = blockIdx.x;
  const float* s;
  f16* d;
  int base;
  if (bid < 4096) {
    s = X; d = Xh; base = bid;
  } else if (bid < 5632) {
    s = W1; d = W1h; base = bid - 4096;
  } else {
    s = W2; d = W2h; base = bid - 5632;
  }
  const int i = (base * 256 + threadIdx.x) * 8;
  const float4 a = *(const float4*)(s + i);
  const float4 b = *(const float4*)(s + i + 4);
  f16x8 o;
  o[0] = (f16)a.x; o[1] = (f16)a.y; o[2] = (f16)a.z; o[3] = (f16)a.w;
  o[4] = (f16)b.x; o[5] = (f16)b.y; o[6] = (f16)b.z; o[7] = (f16)b.w;
  *(f16x8*)(d + i) = o;
}

extern "C" void kernel_launch(void* const* d_in, const int* in_sizes, int n_in,
                              void* d_out, int out_size, void* d_ws,
                              size_t ws_size, hipStream_t stream) {
  const float* X = (const float*)d_in[0];      // (4,2048,1024)
  const int* vlens = (const int*)d_in[1];      // (4,)
  const float* Wkqv = (const float*)d_in[2];   // (3072,1024)
  const float* bkqv = (const float*)d_in[3];   // (3072,)
  const float* Wproj = (const float*)d_in[4];  // (1024,1024)
  const float* bproj = (const float*)d_in[5];  // (1024,)
  float* out = (float*)d_out;                  // (4,2048,1024) f32

  char* w = (char*)d_ws;
  f16* Xh = (f16*)w;      w += 8192L * 1024 * 2;
  f16* Wkqvh = (f16*)w;   w += 3072L * 1024 * 2;
  f16* Wprojh = (f16*)w;  w += 1024L * 1024 * 2;
  f16* kqvh = (f16*)w;    w += 8192L * 3072 * 2;
  f16* attnh = (f16*)w;   w += 4L * 2048 * 2048 * 2;
  f16* out2h = (f16*)w;   w += 8192L * 1024 * 2;
  f16* Sh = (f16*)w;      // 4*2048*2048 f16

  cvt_all<<<6144, 256, 0, stream>>>(X, Wkqv, Wproj, Xh, Wkqvh, Wprojh);

  // G1: kqvh = f16(Xh @ Wkqvh^T + bkqv)   M=8192 N=3072 K=1024
  mfma_gemm<false, true, false, false, true, false>
      <<<dim3(24, 64, 1), 256, 0, stream>>>(Xh, 1024, Wkqvh, 1024, kqvh, 3072,
                                            bkqv, nullptr, 1.0f, 1024, 0, 0, 0);

  // G2: Sh[b] = f16(Qh @ Kh^T * 1/32), masked   M=N=2048 K=1024
  mfma_gemm<false, false, true, false, true, false>
      <<<dim3(16, 16, 4), 256, 0, stream>>>(
          kqvh + 1024, 3072, kqvh, 3072, Sh, 2048, nullptr, vlens, 0.03125f,
          1024, 2048L * 3072, 2048L * 3072, 2048L * 2048);

  // SM: masked softmax rows (f16 in) -> fp16 attn
  softmax_rows<<<8192, 256, 0, stream>>>(Sh, attnh, vlens);

  // G4: out2h = f16(perm(attn @ V))   M=2048 N=1024 K<=2048 (vlen-limited)
  mfma_gemm<true, false, false, true, true, true>
      <<<dim3(8, 16, 4), 256, 0, stream>>>(
          attnh, 2048, kqvh + 2048, 3072, out2h, 1024, nullptr, vlens, 1.0f,
          2048, 2048L * 2048, 2048L * 3072, 2048L * 1024);

  // G5: out = out2h @ Wprojh^T + bproj   M=8192 N=1024 K=1024 (f32 out)
  mfma_gemm<false, true, false, false, false, false>
      <<<dim3(8, 64, 1), 256, 0, stream>>>(out2h, 1024, Wprojh, 1024, out,
                                           1024, bproj, nullptr, 1.0f, 1024, 0,
                                           0, 0);
}

// Round 8
// 232.379 us; speedup vs baseline: 1.3916x; 1.0081x over previous
//
#include <hip/hip_runtime.h>
#include <hip/hip_fp16.h>

// B=4, L=2048, D=1024.  Round-7 proven pipeline (2-phase 128x128 fp16-MFMA
// GEMMs, multi-block/CU overlap) + dead-store elimination:
//   G2 stores only cols < vlen (masked cols never read by softmax)
//   SM stores only cols < ceil32(vlen) (G4's K-loop never reads beyond)
//  cvt (1 dispatch): X, Wkqv, Wproj -> fp16
//  G1: kqvh = f16(Xh @ Wkqvh^T + bkqv)              8192x3072
//  G2: Sh[b] = f16(Qh@Kh^T * 1/32), cols < vlen only; masked col-tiles skipped
//  SM: masked row softmax (f16 in) -> attn f16, cols < ceil32(vlen)
//  G4: out2h = f16(perm(attn @ V)), K limited to ceil(vlen/32) tiles,
//      V reg-staged + pack-transposed ([n][32] layout)
//  G5: out = out2h @ Wprojh^T + bproj (f32 -> d_out)

typedef _Float16 f16;
typedef _Float16 f16x8 __attribute__((ext_vector_type(8)));
typedef float f32x4 __attribute__((ext_vector_type(4)));

#define BM 128
#define BN 128
#define BK 32

__device__ __forceinline__ void gload16(const f16* g, f16* l) {
  __builtin_amdgcn_global_load_lds(
      (const __attribute__((address_space(1))) unsigned int*)g,
      (__attribute__((address_space(3))) unsigned int*)l, 16, 0, 0);
}

// BT: B operand is V (K-major, reg-stage + pack-transpose). Otherwise B is
//     (N,K) row-major fp16, staged via global_load_lds (4 lanes/row, 64B
//     contiguous per row -> 16 segments/instr).
// MASK: scale by `scale`, store only cols < vlen; skip tile if n0>=vlen.
// BIAS: c += bias[col]. PERM: swapaxes-reshape write. OUTF16: f16 C.
// KLIM: K-loop limited to ceil(vlen/BK) tiles.
template <bool BT, bool BIAS, bool MASK, bool PERM, bool OUTF16, bool KLIM>
__global__ __launch_bounds__(256) void mfma_gemm(
    const f16* __restrict__ A, long lda, const f16* __restrict__ B, long ldb,
    void* __restrict__ Cv, long ldc, const float* __restrict__ bias,
    const int* __restrict__ valid_lens, float scale, int K, long strideA,
    long strideB, long strideC) {
  __shared__ __align__(16) f16 As[2][BM * BK];
  __shared__ __align__(16) f16 Bs[2][BN * BK];

  const int tid = threadIdx.x;
  const int w = tid >> 6;
  const int ln = tid & 63;
  const int m0 = blockIdx.y * BM;
  const int n0 = blockIdx.x * BN;
  const int bz = blockIdx.z;

  const int vlen = (MASK || KLIM) ? valid_lens[bz] : 0;
  if (MASK && n0 >= vlen) return;  // fully-masked tile: softmax never reads it

  A += (long)bz * strideA;
  B += (long)bz * strideB;

  int nk = K >> 5;
  if (KLIM) {
    int t = (vlen + BK - 1) >> 5;
    nk = t < nk ? t : nk;
  }

  // V pack-transpose staging indices
  const int kp = tid & 15;  // k-pair index (k = 2*kp, 2*kp+1)
  const int dg = tid >> 4;  // d-group (8 cols)

  f32x4 acc[4][4];
#pragma unroll
  for (int i = 0; i < 4; ++i)
#pragma unroll
    for (int j = 0; j < 4; ++j) acc[i][j] = (f32x4){0.f, 0.f, 0.f, 0.f};

  uint4 va, vb2;

  auto stageA = [&](int buf, int kk) {
#pragma unroll
    for (int r = 0; r < 2; ++r)
      gload16(A + (long)(m0 + r * 64 + w * 16 + (ln >> 2)) * lda + kk +
                  (ln & 3) * 8,
              &As[buf][(r * 64 + w * 16) * BK]);
  };
  auto stageB = [&](int buf, int kk) {
#pragma unroll
    for (int r = 0; r < 2; ++r)
      gload16(B + (long)(n0 + r * 64 + w * 16 + (ln >> 2)) * ldb + kk +
                  (ln & 3) * 8,
              &Bs[buf][(r * 64 + w * 16) * BK]);
  };
  auto loadV = [&](int kk) {
    const f16* p = B + (long)(kk + 2 * kp) * ldb + n0 + dg * 8;
    va = *(const uint4*)p;
    vb2 = *(const uint4*)(p + ldb);
  };
  auto writeV = [&](int buf) {  // [n][32] layout
    unsigned int* bw = (unsigned int*)&Bs[buf][0];
    const unsigned int ax[4] = {va.x, va.y, va.z, va.w};
    const unsigned int bx[4] = {vb2.x, vb2.y, vb2.z, vb2.w};
#pragma unroll
    for (int j = 0; j < 4; ++j) {
      unsigned int lo = (ax[j] & 0xffffu) | (bx[j] << 16);
      unsigned int hi = (ax[j] >> 16) | (bx[j] & 0xffff0000u);
      bw[(dg * 8 + 2 * j) * 16 + kp] = lo;
      bw[(dg * 8 + 2 * j + 1) * 16 + kp] = hi;
    }
  };

  stageA(0, 0);
  if (!BT) {
    stageB(0, 0);
  } else {
    loadV(0);
    writeV(0);
  }
  __syncthreads();

  const int wm = (w >> 1) * 64;
  const int wn = (w & 1) * 64;

  for (int kt = 0; kt < nk; ++kt) {
    const int cur = kt & 1;
    const int nxt = cur ^ 1;
    const bool more = (kt + 1) < nk;
    if (more) {
      stageA(nxt, (kt + 1) << 5);
      if (!BT)
        stageB(nxt, (kt + 1) << 5);
      else
        loadV((kt + 1) << 5);
    }
    f16x8 af[4], bff[4];
#pragma unroll
    for (int i = 0; i < 4; ++i)
      af[i] = *(const f16x8*)&As[cur][(wm + i * 16 + (ln & 15)) * BK +
                                      (ln >> 4) * 8];
#pragma unroll
    for (int j = 0; j < 4; ++j)
      bff[j] = *(const f16x8*)&Bs[cur][(wn + j * 16 + (ln & 15)) * BK +
                                       (ln >> 4) * 8];
#pragma unroll
    for (int i = 0; i < 4; ++i)
#pragma unroll
      for (int j = 0; j < 4; ++j)
        acc[i][j] = __builtin_amdgcn_mfma_f32_16x16x32_f16(af[i], bff[j],
                                                           acc[i][j], 0, 0, 0);
    if (BT && more) writeV(nxt);
    __syncthreads();
  }

  // epilogue (C/D: col = ln&15, row = (ln>>4)*4 + r)
  const int lq = ln >> 4;
  const int lc = ln & 15;
#pragma unroll
  for (int i = 0; i < 4; ++i) {
#pragma unroll
    for (int j = 0; j < 4; ++j) {
      const int col = n0 + wn + j * 16 + lc;
      if (MASK && col >= vlen) continue;  // dead store: softmax never reads it
      const float bv = BIAS ? bias[col] : 0.0f;
#pragma unroll
      for (int r = 0; r < 4; ++r) {
        const int row = m0 + wm + i * 16 + lq * 4 + r;
        float c = acc[i][j][r];
        if (MASK) c = c * scale;
        if (BIAS) c += bv;
        if (PERM) {
          const long idx =
              ((long)bz * 2048 + 2 * col + (row >> 10)) * 1024 + (row & 1023);
          ((f16*)Cv)[idx] = (f16)c;
        } else {
          const long idx = (long)bz * strideC + (long)row * ldc + col;
          if (OUTF16)
            ((f16*)Cv)[idx] = (f16)c;
          else
            ((float*)Cv)[idx] = c;
        }
      }
    }
  }
}

// ================== softmax (f16 scores in, f16 attn out) ==================
__global__ __launch_bounds__(256) void softmax_rows(
    const f16* __restrict__ S, f16* __restrict__ attn,
    const int* __restrict__ vlens) {
  const long row = blockIdx.x;
  const int b = (int)(row >> 11);
  const int vlen = vlens[b];
  const f16* p = S + row * 2048;
  const int tid = threadIdx.x;
  const int wave = tid >> 6, lane = tid & 63;
  const int c0 = tid * 8;

  float v[8];
  if (c0 + 8 <= vlen) {
    const f16x8 a = *(const f16x8*)(p + c0);
#pragma unroll
    for (int j = 0; j < 8; ++j) v[j] = (float)a[j];
  } else {
#pragma unroll
    for (int j = 0; j < 8; ++j)
      v[j] = (c0 + j < vlen) ? (float)p[c0 + j] : -1000000.0f;
  }

  float mx = v[0];
#pragma unroll
  for (int j = 1; j < 8; ++j) mx = fmaxf(mx, v[j]);
#pragma unroll
  for (int o = 1; o < 64; o <<= 1) mx = fmaxf(mx, __shfl_xor(mx, o));
  __shared__ float redm[4];
  if (lane == 0) redm[wave] = mx;
  __syncthreads();
  mx = fmaxf(fmaxf(redm[0], redm[1]), fmaxf(redm[2], redm[3]));

  float s = 0.f;
#pragma unroll
  for (int j = 0; j < 8; ++j) {
    v[j] = __expf(v[j] - mx);
    s += v[j];
  }
#pragma unroll
  for (int o = 1; o < 64; o <<= 1) s += __shfl_xor(s, o);
  __shared__ float reds[4];
  if (lane == 0) reds[wave] = s;
  __syncthreads();
  s = reds[0] + reds[1] + reds[2] + reds[3];

  // G4 reads attn cols only up to ceil32(vlen): skip dead stores beyond.
  if (c0 >= ((vlen + 31) & ~31)) return;

  const float inv = 1.0f / s;
  f16x8 ov;
#pragma unroll
  for (int j = 0; j < 8; ++j) ov[j] = (f16)(v[j] * inv);
  *(f16x8*)(attn + row * 2048 + c0) = ov;
}

// ================== fused f32->f16 convert (1 dispatch) ==================
__global__ __launch_bounds__(256) void cvt_all(
    const float* __restrict__ X, const float* __restrict__ W1,
    const float* __restrict__ W2, f16* __restrict__ Xh, f16* __restrict__ W1h,
    f16* __restrict__ W2h) {
  const int bid = blockIdx.x;
  const float* s;
  f16* d;
  int base;
  if (bid < 4096) {
    s = X; d = Xh; base = bid;
  } else if (bid < 5632) {
    s = W1; d = W1h; base = bid - 4096;
  } else {
    s = W2; d = W2h; base = bid - 5632;
  }
  const int i = (base * 256 + threadIdx.x) * 8;
  const float4 a = *(const float4*)(s + i);
  const float4 b = *(const float4*)(s + i + 4);
  f16x8 o;
  o[0] = (f16)a.x; o[1] = (f16)a.y; o[2] = (f16)a.z; o[3] = (f16)a.w;
  o[4] = (f16)b.x; o[5] = (f16)b.y; o[6] = (f16)b.z; o[7] = (f16)b.w;
  *(f16x8*)(d + i) = o;
}

extern "C" void kernel_launch(void* const* d_in, const int* in_sizes, int n_in,
                              void* d_out, int out_size, void* d_ws,
                              size_t ws_size, hipStream_t stream) {
  const float* X = (const float*)d_in[0];      // (4,2048,1024)
  const int* vlens = (const int*)d_in[1];      // (4,)
  const float* Wkqv = (const float*)d_in[2];   // (3072,1024)
  const float* bkqv = (const float*)d_in[3];   // (3072,)
  const float* Wproj = (const float*)d_in[4];  // (1024,1024)
  const float* bproj = (const float*)d_in[5];  // (1024,)
  float* out = (float*)d_out;                  // (4,2048,1024) f32

  char* w = (char*)d_ws;
  f16* Xh = (f16*)w;      w += 8192L * 1024 * 2;
  f16* Wkqvh = (f16*)w;   w += 3072L * 1024 * 2;
  f16* Wprojh = (f16*)w;  w += 1024L * 1024 * 2;
  f16* kqvh = (f16*)w;    w += 8192L * 3072 * 2;
  f16* attnh = (f16*)w;   w += 4L * 2048 * 2048 * 2;
  f16* out2h = (f16*)w;   w += 8192L * 1024 * 2;
  f16* Sh = (f16*)w;      // 4*2048*2048 f16

  cvt_all<<<6144, 256, 0, stream>>>(X, Wkqv, Wproj, Xh, Wkqvh, Wprojh);

  // G1: kqvh = f16(Xh @ Wkqvh^T + bkqv)   M=8192 N=3072 K=1024
  mfma_gemm<false, true, false, false, true, false>
      <<<dim3(24, 64, 1), 256, 0, stream>>>(Xh, 1024, Wkqvh, 1024, kqvh, 3072,
                                            bkqv, nullptr, 1.0f, 1024, 0, 0, 0);

  // G2: Sh[b] = f16(Qh @ Kh^T * 1/32), cols < vlen   M=N=2048 K=1024
  mfma_gemm<false, false, true, false, true, false>
      <<<dim3(16, 16, 4), 256, 0, stream>>>(
          kqvh + 1024, 3072, kqvh, 3072, Sh, 2048, nullptr, vlens, 0.03125f,
          1024, 2048L * 3072, 2048L * 3072, 2048L * 2048);

  // SM: masked softmax rows (f16 in) -> fp16 attn (cols < ceil32(vlen))
  softmax_rows<<<8192, 256, 0, stream>>>(Sh, attnh, vlens);

  // G4: out2h = f16(perm(attn @ V))   M=2048 N=1024 K<=2048 (vlen-limited)
  mfma_gemm<true, false, false, true, true, true>
      <<<dim3(8, 16, 4), 256, 0, stream>>>(
          attnh, 2048, kqvh + 2048, 3072, out2h, 1024, nullptr, vlens, 1.0f,
          2048, 2048L * 2048, 2048L * 3072, 2048L * 1024);

  // G5: out = out2h @ Wprojh^T + bproj   M=8192 N=1024 K=1024 (f32 out)
  mfma_gemm<false, true, false, false, false, false>
      <<<dim3(8, 64, 1), 256, 0, stream>>>(out2h, 1024, Wprojh, 1024, out,
                                           1024, bproj, nullptr, 1.0f, 1024, 0,
                                           0, 0);
}